// Round 5
// baseline (130.922 us; speedup 1.0000x reference)
//
#include <hip/hip_runtime.h>

#define NN 2048
#define DD 128
#define KK 16
#define DIRTY 0xFFFFFFFFFFFFFFFFull

typedef float f4 __attribute__((ext_vector_type(4)));

// Sortable key: (value desc, index asc). Valid scores are uniform [0,1); +1 keeps
// key>0 so 0 means "no candidate". Low 11 bits = 2047-j so larger key == smaller
// index at equal value (matches jax top_k stable tie-break). Max key < 2^42, so
// all-ones (DIRTY) never collides with a real key.
__device__ __forceinline__ unsigned long long packkey(float v, int j) {
    unsigned long long k = ((unsigned long long)(__float_as_uint(v) + 1u) << 11)
                         | (unsigned int)(2047 - j);
    return (v >= 0.0f) ? k : 0ull;
}

// 256-thread blocks = 4 independent waves, one row (b,i) per wave. No LDS, no
// __syncthreads. Lane owns indices j = t*256 + lane*4 + c; rescans (rare with a
// top-3 cache) re-read own elements from L2-hot global with selmask exclusion.
__global__ __launch_bounds__(256, 8) void rc_topk_kernel(
    const float* __restrict__ s,        // [B,N,D]
    const float* __restrict__ noise,    // [B,N,N]
    const int*   __restrict__ adj,      // [B,N,N]
    const int*   __restrict__ active,   // [B,N]
    const int*   __restrict__ act,      // [B,N]
    float* __restrict__ ctx,            // [B,N,D]
    float* __restrict__ gate,           // [B,N,N]
    float* __restrict__ w)
{
    const int lane = threadIdx.x & 63;
    const int wid  = threadIdx.x >> 6;
    // XCD-chunked bijective swizzle: nwg = B*512 (always % 8 == 0); each XCD gets
    // a contiguous chunk of rows -> one batch's s/active stays hot in its L2.
    const int nwg  = gridDim.x;
    const int o    = blockIdx.x;
    const int bid  = (o & 7) * (nwg >> 3) + (o >> 3);
    const int row  = (bid << 2) + wid;     // b*N + i
    const int b    = row >> 11;
    const long long rowoff = (long long)row * NN;

    if (act[row] == 0) {
        const f4 z4 = (f4)0.0f;
        #pragma unroll
        for (int t = 0; t < 8; ++t) {
            const int j = t * 256 + lane * 4;
            *(f4*)&gate[rowoff + j] = z4;
            *(f4*)&w[rowoff + j]    = z4;
        }
        *(float2*)&ctx[(long long)row * DD + lane * 2] = make_float2(0.f, 0.f);
        return;
    }

    // ---- Pass 1: per-lane top-3 (ascending j, strict '>' => min index on ties) ----
    float v1 = -4.0f, v2 = -4.0f, v3 = -4.0f; int j1 = 0, j2 = 0, j3 = 0;
    #pragma unroll
    for (int t = 0; t < 8; ++t) {
        const int j = t * 256 + lane * 4;
        const float4 nz = *(const float4*)&noise[rowoff + j];
        const int4   ad = *(const int4*)&adj[rowoff + j];
        const int4   am = *(const int4*)&active[b * NN + j];
        #pragma unroll
        for (int c = 0; c < 4; ++c) {
            const float nv = c == 0 ? nz.x : c == 1 ? nz.y : c == 2 ? nz.z : nz.w;
            const int   av = c == 0 ? ad.x : c == 1 ? ad.y : c == 2 ? ad.z : ad.w;
            const int   mv = c == 0 ? am.x : c == 1 ? am.y : c == 2 ? am.z : am.w;
            const float v  = (av > 0 && mv > 0) ? nv : -1.0f;
            if (v > v1)      { v3 = v2; j3 = j2; v2 = v1; j2 = j1; v1 = v; j1 = j + c; }
            else if (v > v2) { v3 = v2; j3 = j2; v2 = v;  j2 = j + c; }
            else if (v > v3) { v3 = v;  j3 = j + c; }
        }
    }
    unsigned long long k1 = packkey(v1, j1);
    unsigned long long k2 = packkey(v2, j2);
    unsigned long long k3 = packkey(v3, j3);
    unsigned int selmask = 0;              // bit (t*4+c): own element selected

    // ---- 16x extraction: u64 butterfly max (winner index embedded in key) ----
    int cnt = 0;
    float2 acc  = make_float2(0.f, 0.f);
    float2 pend = make_float2(0.f, 0.f);
    for (int k = 0; k < KK; ++k) {
        unsigned long long rk = k1;
        #pragma unroll
        for (int off = 32; off; off >>= 1) {
            const unsigned long long oth = __shfl_xor(rk, off, 64);
            if (oth > rk) rk = oth;
        }
        if (rk == 0ull) break;             // no valid candidates left
        acc.x += pend.x; acc.y += pend.y;  // consume previous iteration's s-load
        const int rj = 2047 - (int)((unsigned int)rk & 0x7FFu);
        pend = *(const float2*)&s[((long long)(b * NN + rj)) * DD + lane * 2];
        ++cnt;
        if (k1 == rk) {                    // unique owner lane
            selmask |= 1u << (((rj >> 8) << 2) | (rj & 3));
            if (k2 != DIRTY) { k1 = k2; k2 = k3; k3 = DIRTY; }
            else {                         // 3rd win: rescan own 32 from L2
                float c1v = -4.0f, c2v = -4.0f, c3v = -4.0f;
                int   c1j = 0,     c2j = 0,     c3j = 0;
                #pragma unroll
                for (int t = 0; t < 8; ++t) {
                    const int j = t * 256 + lane * 4;
                    const float4 nz = *(const float4*)&noise[rowoff + j];
                    const int4   ad = *(const int4*)&adj[rowoff + j];
                    const int4   am = *(const int4*)&active[b * NN + j];
                    const unsigned mb = selmask >> (t * 4);
                    #pragma unroll
                    for (int c = 0; c < 4; ++c) {
                        const float nv = c == 0 ? nz.x : c == 1 ? nz.y : c == 2 ? nz.z : nz.w;
                        const int   av = c == 0 ? ad.x : c == 1 ? ad.y : c == 2 ? ad.z : ad.w;
                        const int   mv = c == 0 ? am.x : c == 1 ? am.y : c == 2 ? am.z : am.w;
                        const float v = (av > 0 && mv > 0 && !(mb & (1u << c))) ? nv : -1.0f;
                        if (v > c1v)      { c3v = c2v; c3j = c2j; c2v = c1v; c2j = c1j; c1v = v; c1j = j + c; }
                        else if (v > c2v) { c3v = c2v; c3j = c2j; c2v = v;  c2j = j + c; }
                        else if (v > c3v) { c3v = v;  c3j = j + c; }
                    }
                }
                k1 = packkey(c1v, c1j);
                k2 = packkey(c2v, c2j);
                k3 = packkey(c3v, c3j);
            }
        }
    }
    acc.x += pend.x; acc.y += pend.y;      // last pending row

    const float inv = 1.0f / (float)(cnt > 1 ? cnt : 1);

    // ---- Output stream: gate/w rebuilt from selmask (lane owns every address) ----
    #pragma unroll
    for (int t = 0; t < 8; ++t) {
        const int j = t * 256 + lane * 4;
        const unsigned mb = selmask >> (t * 4);
        f4 g;
        g.x = (mb & 1u) ? 1.0f : 0.0f;
        g.y = (mb & 2u) ? 1.0f : 0.0f;
        g.z = (mb & 4u) ? 1.0f : 0.0f;
        g.w = (mb & 8u) ? 1.0f : 0.0f;
        *(f4*)&gate[rowoff + j] = g;
        *(f4*)&w[rowoff + j]    = g * inv;
    }

    // ---- ctx ----
    *(float2*)&ctx[(long long)row * DD + lane * 2] = make_float2(acc.x * inv, acc.y * inv);
}

extern "C" void kernel_launch(void* const* d_in, const int* in_sizes, int n_in,
                              void* d_out, int out_size, void* d_ws, size_t ws_size,
                              hipStream_t stream) {
    const float* s      = (const float*)d_in[0];
    const float* noise  = (const float*)d_in[1];
    const int*   adj    = (const int*)d_in[2];
    const int*   active = (const int*)d_in[3];
    const int*   act    = (const int*)d_in[4];

    const int B = in_sizes[3] / NN;                  // active_mask is [B,N]
    const long long ctxN  = (long long)B * NN * DD;
    const long long gateN = (long long)B * NN * NN;

    float* ctxp  = (float*)d_out;
    float* gatep = ctxp + ctxN;
    float* wp    = gatep + gateN;

    rc_topk_kernel<<<(B * NN) / 4, 256, 0, stream>>>(s, noise, adj, active, act,
                                                     ctxp, gatep, wp);
}

// Round 6
// 105.472 us; speedup vs baseline: 1.2413x; 1.2413x over previous
//
#include <hip/hip_runtime.h>

#define NN 2048
#define DD 128
#define KK 16
#define DIRTY 0xFFFFFFFFFFFFFFFFull

typedef float f4 __attribute__((ext_vector_type(4)));

// Sortable key: (value desc, index asc). Valid scores are uniform [0,1); +1 keeps
// key>0 so 0 means "no candidate". Low 11 bits = 2047-j so larger key == smaller
// index at equal value (matches jax top_k stable tie-break). Real keys < 2^42, so
// DIRTY (all ones) never collides.
__device__ __forceinline__ unsigned long long packkey(float v, int j) {
    unsigned long long k = ((unsigned long long)(__float_as_uint(v) + 1u) << 11)
                         | (unsigned int)(2047 - j);
    return (v >= 0.0f) ? k : 0ull;
}

// One wave (64 threads) per output row (b,i). Lane owns j = t*256 + lane*4 + c.
// Scores stashed in LDS; rescans (rare with top-3 cache) re-read own 32 from LDS.
__global__ __launch_bounds__(64) void rc_topk_kernel(
    const float* __restrict__ s,        // [B,N,D]
    const float* __restrict__ noise,    // [B,N,N]
    const int*   __restrict__ adj,      // [B,N,N]
    const int*   __restrict__ active,   // [B,N]
    const int*   __restrict__ act,      // [B,N]
    float* __restrict__ ctx,            // [B,N,D]
    float* __restrict__ gate,           // [B,N,N]
    float* __restrict__ w)
{
    __shared__ float sc[NN];

    const int lane = threadIdx.x;          // 0..63
    const int row  = blockIdx.x;           // b*N + i
    const int b    = row >> 11;
    const long long rowoff = (long long)row * NN;

    if (act[row] == 0) {
        const f4 z4 = (f4)0.0f;
        #pragma unroll
        for (int t = 0; t < 8; ++t) {
            const int j = t * 256 + lane * 4;
            *(f4*)&gate[rowoff + j] = z4;
            *(f4*)&w[rowoff + j]    = z4;
        }
        *(float2*)&ctx[(long long)row * DD + lane * 2] = make_float2(0.f, 0.f);
        return;
    }

    // ---- Pass 1: score + stash in LDS + per-lane top-3 (strict '>' => min index) ----
    float v1 = -4.0f, v2 = -4.0f, v3 = -4.0f; int j1 = 0, j2 = 0, j3 = 0;
    #pragma unroll
    for (int t = 0; t < 8; ++t) {
        const int j = t * 256 + lane * 4;
        const float4 nz = *(const float4*)&noise[rowoff + j];
        const int4   ad = *(const int4*)&adj[rowoff + j];
        const int4   am = *(const int4*)&active[b * NN + j];
        f4 sv;
        #pragma unroll
        for (int c = 0; c < 4; ++c) {
            const float nv = c == 0 ? nz.x : c == 1 ? nz.y : c == 2 ? nz.z : nz.w;
            const int   av = c == 0 ? ad.x : c == 1 ? ad.y : c == 2 ? ad.z : ad.w;
            const int   mv = c == 0 ? am.x : c == 1 ? am.y : c == 2 ? am.z : am.w;
            const float v  = (av > 0 && mv > 0) ? nv : -1.0f;
            sv[c] = v;
            if (v > v1)      { v3 = v2; j3 = j2; v2 = v1; j2 = j1; v1 = v; j1 = j + c; }
            else if (v > v2) { v3 = v2; j3 = j2; v2 = v;  j2 = j + c; }
            else if (v > v3) { v3 = v;  j3 = j + c; }
        }
        *(f4*)&sc[j] = sv;
    }
    unsigned long long k1 = packkey(v1, j1);
    unsigned long long k2 = packkey(v2, j2);
    unsigned long long k3 = packkey(v3, j3);
    unsigned int selmask = 0;              // bit (t*4+c): own element selected

    // ---- 16x extraction: u64 butterfly max (winner index embedded in key) ----
    int cnt = 0;
    float2 acc  = make_float2(0.f, 0.f);
    float2 pend = make_float2(0.f, 0.f);
    for (int k = 0; k < KK; ++k) {
        unsigned long long rk = k1;
        #pragma unroll
        for (int off = 32; off; off >>= 1) {
            const unsigned long long oth = __shfl_xor(rk, off, 64);
            if (oth > rk) rk = oth;
        }
        if (rk == 0ull) break;             // no valid candidates left
        acc.x += pend.x; acc.y += pend.y;  // consume previous iteration's s-load
        const int rj = 2047 - (int)((unsigned int)rk & 0x7FFu);
        pend = *(const float2*)&s[((long long)(b * NN + rj)) * DD + lane * 2];
        ++cnt;
        if (k1 == rk) {                    // unique owner lane
            selmask |= 1u << (((rj >> 8) << 2) | (rj & 3));
            sc[rj] = -2.0f;                // consume own LDS slot
            if (k2 != DIRTY) { k1 = k2; k2 = k3; k3 = DIRTY; }
            else {                         // 3rd win: rescan own 32 from LDS
                float c1v = -4.0f, c2v = -4.0f, c3v = -4.0f;
                int   c1j = 0,     c2j = 0,     c3j = 0;
                #pragma unroll
                for (int t = 0; t < 8; ++t) {
                    const int j = t * 256 + lane * 4;
                    const f4 q = *(const f4*)&sc[j];
                    #pragma unroll
                    for (int c = 0; c < 4; ++c) {
                        const float v = q[c];
                        if (v > c1v)      { c3v = c2v; c3j = c2j; c2v = c1v; c2j = c1j; c1v = v; c1j = j + c; }
                        else if (v > c2v) { c3v = c2v; c3j = c2j; c2v = v;  c2j = j + c; }
                        else if (v > c3v) { c3v = v;  c3j = j + c; }
                    }
                }
                k1 = packkey(c1v, c1j);
                k2 = packkey(c2v, c2j);
                k3 = packkey(c3v, c3j);
            }
        }
    }
    acc.x += pend.x; acc.y += pend.y;      // last pending row

    const float inv = 1.0f / (float)(cnt > 1 ? cnt : 1);

    // ---- Output stream: gate/w from selmask (lane owns every address), plain stores ----
    #pragma unroll
    for (int t = 0; t < 8; ++t) {
        const int j = t * 256 + lane * 4;
        const unsigned mb = selmask >> (t * 4);
        f4 g;
        g.x = (mb & 1u) ? 1.0f : 0.0f;
        g.y = (mb & 2u) ? 1.0f : 0.0f;
        g.z = (mb & 4u) ? 1.0f : 0.0f;
        g.w = (mb & 8u) ? 1.0f : 0.0f;
        *(f4*)&gate[rowoff + j] = g;
        *(f4*)&w[rowoff + j]    = g * inv;
    }

    // ---- ctx ----
    *(float2*)&ctx[(long long)row * DD + lane * 2] = make_float2(acc.x * inv, acc.y * inv);
}

extern "C" void kernel_launch(void* const* d_in, const int* in_sizes, int n_in,
                              void* d_out, int out_size, void* d_ws, size_t ws_size,
                              hipStream_t stream) {
    const float* s      = (const float*)d_in[0];
    const float* noise  = (const float*)d_in[1];
    const int*   adj    = (const int*)d_in[2];
    const int*   active = (const int*)d_in[3];
    const int*   act    = (const int*)d_in[4];

    const int B = in_sizes[3] / NN;                  // active_mask is [B,N]
    const long long ctxN  = (long long)B * NN * DD;
    const long long gateN = (long long)B * NN * NN;

    float* ctxp  = (float*)d_out;
    float* gatep = ctxp + ctxN;
    float* wp    = gatep + gateN;

    rc_topk_kernel<<<B * NN, 64, 0, stream>>>(s, noise, adj, active, act,
                                              ctxp, gatep, wp);
}

// Round 7
// 87.579 us; speedup vs baseline: 1.4949x; 1.2043x over previous
//
#include <hip/hip_runtime.h>

#define NN 2048
#define DD 128
#define KK 16
#define DIRTY 0xFFFFFFFFFFFFFFFFull

typedef float f4 __attribute__((ext_vector_type(4)));

// Sortable key: (value desc, index asc). Valid scores are uniform [0,1); +1 keeps
// key>0 so 0 means "no candidate". Low 11 bits = 2047-j so larger key == smaller
// index at equal value (matches jax top_k stable tie-break). Real keys < 2^42, so
// DIRTY (all ones) never collides.
__device__ __forceinline__ unsigned long long packkey(float v, int j) {
    unsigned long long k = ((unsigned long long)(__float_as_uint(v) + 1u) << 11)
                         | (unsigned int)(2047 - j);
    return (v >= 0.0f) ? k : 0ull;
}

// 256-thread blocks = 4 independent waves, one row (b,i) per wave, private 8KB LDS
// slice each, zero __syncthreads. Lane owns j = t*256 + lane*4 + c. All output
// stores nontemporal (bypass L2 -> keep L2 for noise/adj/s; measured +40% vs plain).
__global__ __launch_bounds__(256, 5) void rc_topk_kernel(
    const float* __restrict__ s,        // [B,N,D]
    const float* __restrict__ noise,    // [B,N,N]
    const int*   __restrict__ adj,      // [B,N,N]
    const int*   __restrict__ active,   // [B,N]
    const int*   __restrict__ act,      // [B,N]
    float* __restrict__ ctx,            // [B,N,D]
    float* __restrict__ gate,           // [B,N,N]
    float* __restrict__ w)
{
    __shared__ float sc_all[4][NN];

    const int lane = threadIdx.x & 63;
    const int wid  = threadIdx.x >> 6;
    float* sc = sc_all[wid];

    // XCD-chunked bijective swizzle (nwg = B*512, always %8==0): contiguous rows
    // per XCD so each XCD's L2 holds one batch's s/active.
    const int nwg = gridDim.x;
    const int o   = blockIdx.x;
    const int bid = (o & 7) * (nwg >> 3) + (o >> 3);
    const int row = (bid << 2) + wid;      // b*N + i
    const int b   = row >> 11;
    const long long rowoff = (long long)row * NN;

    if (act[row] == 0) {
        const f4 z4 = (f4)0.0f;
        #pragma unroll
        for (int t = 0; t < 8; ++t) {
            const int j = t * 256 + lane * 4;
            __builtin_nontemporal_store(z4, (f4*)&gate[rowoff + j]);
            __builtin_nontemporal_store(z4, (f4*)&w[rowoff + j]);
        }
        *(float2*)&ctx[(long long)row * DD + lane * 2] = make_float2(0.f, 0.f);
        return;
    }

    // ---- Pass 1: score + stash in LDS + per-lane top-3 (strict '>' => min index) ----
    float v1 = -4.0f, v2 = -4.0f, v3 = -4.0f; int j1 = 0, j2 = 0, j3 = 0;
    #pragma unroll
    for (int t = 0; t < 8; ++t) {
        const int j = t * 256 + lane * 4;
        const float4 nz = *(const float4*)&noise[rowoff + j];
        const int4   ad = *(const int4*)&adj[rowoff + j];
        const int4   am = *(const int4*)&active[b * NN + j];
        f4 sv;
        #pragma unroll
        for (int c = 0; c < 4; ++c) {
            const float nv = c == 0 ? nz.x : c == 1 ? nz.y : c == 2 ? nz.z : nz.w;
            const int   av = c == 0 ? ad.x : c == 1 ? ad.y : c == 2 ? ad.z : ad.w;
            const int   mv = c == 0 ? am.x : c == 1 ? am.y : c == 2 ? am.z : am.w;
            const float v  = (av > 0 && mv > 0) ? nv : -1.0f;
            sv[c] = v;
            if (v > v1)      { v3 = v2; j3 = j2; v2 = v1; j2 = j1; v1 = v; j1 = j + c; }
            else if (v > v2) { v3 = v2; j3 = j2; v2 = v;  j2 = j + c; }
            else if (v > v3) { v3 = v;  j3 = j + c; }
        }
        *(f4*)&sc[j] = sv;
    }
    unsigned long long k1 = packkey(v1, j1);
    unsigned long long k2 = packkey(v2, j2);
    unsigned long long k3 = packkey(v3, j3);
    unsigned int selmask = 0;              // bit (t*4+c): own element selected

    // ---- 16x extraction: u64 butterfly max (winner index embedded in key) ----
    int cnt = 0;
    float2 acc  = make_float2(0.f, 0.f);
    float2 pend = make_float2(0.f, 0.f);
    for (int k = 0; k < KK; ++k) {
        unsigned long long rk = k1;
        #pragma unroll
        for (int off = 32; off; off >>= 1) {
            const unsigned long long oth = __shfl_xor(rk, off, 64);
            if (oth > rk) rk = oth;
        }
        if (rk == 0ull) break;             // no valid candidates left
        acc.x += pend.x; acc.y += pend.y;  // consume previous iteration's s-load
        const int rj = 2047 - (int)((unsigned int)rk & 0x7FFu);
        pend = *(const float2*)&s[((long long)(b * NN + rj)) * DD + lane * 2];
        ++cnt;
        if (k1 == rk) {                    // unique owner lane
            selmask |= 1u << (((rj >> 8) << 2) | (rj & 3));
            sc[rj] = -2.0f;                // consume own LDS slot
            if (k2 != DIRTY) { k1 = k2; k2 = k3; k3 = DIRTY; }
            else {                         // 3rd win: rescan own 32 from LDS
                float c1v = -4.0f, c2v = -4.0f, c3v = -4.0f;
                int   c1j = 0,     c2j = 0,     c3j = 0;
                #pragma unroll
                for (int t = 0; t < 8; ++t) {
                    const int j = t * 256 + lane * 4;
                    const f4 q = *(const f4*)&sc[j];
                    #pragma unroll
                    for (int c = 0; c < 4; ++c) {
                        const float v = q[c];
                        if (v > c1v)      { c3v = c2v; c3j = c2j; c2v = c1v; c2j = c1j; c1v = v; c1j = j + c; }
                        else if (v > c2v) { c3v = c2v; c3j = c2j; c2v = v;  c2j = j + c; }
                        else if (v > c3v) { c3v = v;  c3j = j + c; }
                    }
                }
                k1 = packkey(c1v, c1j);
                k2 = packkey(c2v, c2j);
                k3 = packkey(c3v, c3j);
            }
        }
    }
    acc.x += pend.x; acc.y += pend.y;      // last pending row

    const float inv = 1.0f / (float)(cnt > 1 ? cnt : 1);

    // ---- Output stream: gate/w from selmask (lane owns every address), NT stores ----
    #pragma unroll
    for (int t = 0; t < 8; ++t) {
        const int j = t * 256 + lane * 4;
        const unsigned mb = selmask >> (t * 4);
        f4 g;
        g.x = (mb & 1u) ? 1.0f : 0.0f;
        g.y = (mb & 2u) ? 1.0f : 0.0f;
        g.z = (mb & 4u) ? 1.0f : 0.0f;
        g.w = (mb & 8u) ? 1.0f : 0.0f;
        __builtin_nontemporal_store(g, (f4*)&gate[rowoff + j]);
        const f4 wv = g * inv;
        __builtin_nontemporal_store(wv, (f4*)&w[rowoff + j]);
    }

    // ---- ctx ----
    *(float2*)&ctx[(long long)row * DD + lane * 2] = make_float2(acc.x * inv, acc.y * inv);
}

extern "C" void kernel_launch(void* const* d_in, const int* in_sizes, int n_in,
                              void* d_out, int out_size, void* d_ws, size_t ws_size,
                              hipStream_t stream) {
    const float* s      = (const float*)d_in[0];
    const float* noise  = (const float*)d_in[1];
    const int*   adj    = (const int*)d_in[2];
    const int*   active = (const int*)d_in[3];
    const int*   act    = (const int*)d_in[4];

    const int B = in_sizes[3] / NN;                  // active_mask is [B,N]
    const long long ctxN  = (long long)B * NN * DD;
    const long long gateN = (long long)B * NN * NN;

    float* ctxp  = (float*)d_out;
    float* gatep = ctxp + ctxN;
    float* wp    = gatep + gateN;

    rc_topk_kernel<<<(B * NN) / 4, 256, 0, stream>>>(s, noise, adj, active, act,
                                                     ctxp, gatep, wp);
}

// Round 8
// 72.081 us; speedup vs baseline: 1.8163x; 1.2150x over previous
//
#include <hip/hip_runtime.h>

#define NN 2048
#define DD 128
#define KK 16
#define DIRTY 0xFFFFFFFFFFFFFFFFull

typedef float f4 __attribute__((ext_vector_type(4)));

// Sortable key: (value desc, index asc). Valid scores are uniform [0,1); +1 keeps
// key>0 so 0 means "no candidate". Low 11 bits = 2047-j so larger key == smaller
// index at equal value (matches jax top_k stable tie-break). Real keys < 2^42, so
// DIRTY (all ones) never collides.
__device__ __forceinline__ unsigned long long packkey(float v, int j) {
    unsigned long long k = ((unsigned long long)(__float_as_uint(v) + 1u) << 11)
                         | (unsigned int)(2047 - j);
    return (v >= 0.0f) ? k : 0ull;
}

// One wave (64 threads) per row (b,i): per-row block release avoids wave-packing
// tail loss (4-wave blocks measured +13us). Lane owns j = t*256 + lane*4 + c.
// Scores stashed in LDS; rescans (rare with top-3 cache) re-read own 32 from LDS.
// NT stores bypass L2 for the 277MB write stream (measured ~30us vs plain).
__global__ __launch_bounds__(64) void rc_topk_kernel(
    const float* __restrict__ s,        // [B,N,D]
    const float* __restrict__ noise,    // [B,N,N]
    const int*   __restrict__ adj,      // [B,N,N]
    const int*   __restrict__ active,   // [B,N]
    const int*   __restrict__ act,      // [B,N]
    float* __restrict__ ctx,            // [B,N,D]
    float* __restrict__ gate,           // [B,N,N]
    float* __restrict__ w)
{
    __shared__ float sc[NN];

    const int lane = threadIdx.x;          // 0..63
    const int row  = blockIdx.x;           // b*N + i
    const int b    = row >> 11;
    const long long rowoff = (long long)row * NN;

    if (act[row] == 0) {
        const f4 z4 = (f4)0.0f;
        #pragma unroll
        for (int t = 0; t < 8; ++t) {
            const int j = t * 256 + lane * 4;
            __builtin_nontemporal_store(z4, (f4*)&gate[rowoff + j]);
            __builtin_nontemporal_store(z4, (f4*)&w[rowoff + j]);
        }
        *(float2*)&ctx[(long long)row * DD + lane * 2] = make_float2(0.f, 0.f);
        return;
    }

    // ---- Pass 1: score + stash in LDS + per-lane top-3 (strict '>' => min index) ----
    float v1 = -4.0f, v2 = -4.0f, v3 = -4.0f; int j1 = 0, j2 = 0, j3 = 0;
    #pragma unroll
    for (int t = 0; t < 8; ++t) {
        const int j = t * 256 + lane * 4;
        const float4 nz = *(const float4*)&noise[rowoff + j];
        const int4   ad = *(const int4*)&adj[rowoff + j];
        const int4   am = *(const int4*)&active[b * NN + j];
        f4 sv;
        #pragma unroll
        for (int c = 0; c < 4; ++c) {
            const float nv = c == 0 ? nz.x : c == 1 ? nz.y : c == 2 ? nz.z : nz.w;
            const int   av = c == 0 ? ad.x : c == 1 ? ad.y : c == 2 ? ad.z : ad.w;
            const int   mv = c == 0 ? am.x : c == 1 ? am.y : c == 2 ? am.z : am.w;
            const float v  = (av > 0 && mv > 0) ? nv : -1.0f;
            sv[c] = v;
            if (v > v1)      { v3 = v2; j3 = j2; v2 = v1; j2 = j1; v1 = v; j1 = j + c; }
            else if (v > v2) { v3 = v2; j3 = j2; v2 = v;  j2 = j + c; }
            else if (v > v3) { v3 = v;  j3 = j + c; }
        }
        *(f4*)&sc[j] = sv;
    }
    unsigned long long k1 = packkey(v1, j1);
    unsigned long long k2 = packkey(v2, j2);
    unsigned long long k3 = packkey(v3, j3);
    unsigned int selmask = 0;              // bit (t*4+c): own element selected

    // ---- 16x extraction: u64 butterfly max (winner index embedded in key) ----
    int cnt = 0;
    float2 acc  = make_float2(0.f, 0.f);
    float2 pend = make_float2(0.f, 0.f);
    for (int k = 0; k < KK; ++k) {
        unsigned long long rk = k1;
        #pragma unroll
        for (int off = 32; off; off >>= 1) {
            const unsigned long long oth = __shfl_xor(rk, off, 64);
            if (oth > rk) rk = oth;
        }
        if (rk == 0ull) break;             // no valid candidates left
        acc.x += pend.x; acc.y += pend.y;  // consume previous iteration's s-load
        const int rj = 2047 - (int)((unsigned int)rk & 0x7FFu);
        pend = *(const float2*)&s[((long long)(b * NN + rj)) * DD + lane * 2];
        ++cnt;
        if (k1 == rk) {                    // unique owner lane
            selmask |= 1u << (((rj >> 8) << 2) | (rj & 3));
            sc[rj] = -2.0f;                // consume own LDS slot
            if (k2 != DIRTY) { k1 = k2; k2 = k3; k3 = DIRTY; }
            else {                         // 3rd win: rescan own 32 from LDS
                float c1v = -4.0f, c2v = -4.0f, c3v = -4.0f;
                int   c1j = 0,     c2j = 0,     c3j = 0;
                #pragma unroll
                for (int t = 0; t < 8; ++t) {
                    const int j = t * 256 + lane * 4;
                    const f4 q = *(const f4*)&sc[j];
                    #pragma unroll
                    for (int c = 0; c < 4; ++c) {
                        const float v = q[c];
                        if (v > c1v)      { c3v = c2v; c3j = c2j; c2v = c1v; c2j = c1j; c1v = v; c1j = j + c; }
                        else if (v > c2v) { c3v = c2v; c3j = c2j; c2v = v;  c2j = j + c; }
                        else if (v > c3v) { c3v = v;  c3j = j + c; }
                    }
                }
                k1 = packkey(c1v, c1j);
                k2 = packkey(c2v, c2j);
                k3 = packkey(c3v, c3j);
            }
        }
    }
    acc.x += pend.x; acc.y += pend.y;      // last pending row

    const float inv = 1.0f / (float)(cnt > 1 ? cnt : 1);

    // ---- Output stream: gate/w from selmask (lane owns every address), NT stores ----
    #pragma unroll
    for (int t = 0; t < 8; ++t) {
        const int j = t * 256 + lane * 4;
        const unsigned mb = selmask >> (t * 4);
        f4 g;
        g.x = (mb & 1u) ? 1.0f : 0.0f;
        g.y = (mb & 2u) ? 1.0f : 0.0f;
        g.z = (mb & 4u) ? 1.0f : 0.0f;
        g.w = (mb & 8u) ? 1.0f : 0.0f;
        __builtin_nontemporal_store(g, (f4*)&gate[rowoff + j]);
        const f4 wv = g * inv;
        __builtin_nontemporal_store(wv, (f4*)&w[rowoff + j]);
    }

    // ---- ctx ----
    *(float2*)&ctx[(long long)row * DD + lane * 2] = make_float2(acc.x * inv, acc.y * inv);
}

extern "C" void kernel_launch(void* const* d_in, const int* in_sizes, int n_in,
                              void* d_out, int out_size, void* d_ws, size_t ws_size,
                              hipStream_t stream) {
    const float* s      = (const float*)d_in[0];
    const float* noise  = (const float*)d_in[1];
    const int*   adj    = (const int*)d_in[2];
    const int*   active = (const int*)d_in[3];
    const int*   act    = (const int*)d_in[4];

    const int B = in_sizes[3] / NN;                  // active_mask is [B,N]
    const long long ctxN  = (long long)B * NN * DD;
    const long long gateN = (long long)B * NN * NN;

    float* ctxp  = (float*)d_out;
    float* gatep = ctxp + ctxN;
    float* wp    = gatep + gateN;

    rc_topk_kernel<<<B * NN, 64, 0, stream>>>(s, noise, adj, active, act,
                                              ctxp, gatep, wp);
}